// Round 1
// baseline (206.320 us; speedup 1.0000x reference)
//
#include <hip/hip_runtime.h>

// Problem constants (fixed by the reference): B=16 lists, N=1024, D=256.
#define BL 16
#define NL 1024
#define DD 256

typedef short bf16x8 __attribute__((ext_vector_type(8)));
typedef float f32x4 __attribute__((ext_vector_type(4)));

static __device__ __forceinline__ short f32_to_bf16(float f) {
  union { float f; unsigned u; } v; v.f = f;
  unsigned r = (v.u + 0x7FFFu + ((v.u >> 16) & 1u)) >> 16;  // RNE
  return (short)r;
}

// MFMA 16x16x32 bf16 fragment load: lane holds row (r=lane&15) of a row-major
// [16 x K] operand, 8 contiguous bf16 at k = k0 + quad*8  (quad=lane>>4).
// Verified layout (learn_hip m89/m92): A[m=lane&15][k=quad*8+j]; B^T same.
static __device__ __forceinline__ bf16x8 load_frag(const short* __restrict__ base,
                                                   int row0, int k0, int r, int quad) {
  return *(const bf16x8*)(base + (size_t)(row0 + r) * DD + k0 + quad * 8);
}

// ---- Kernel 1: convert feats fp32 -> bf16 (row-major [B*N, D]) ----
__global__ __launch_bounds__(256) void k_convert_x(const float* __restrict__ X,
                                                   short* __restrict__ Xb) {
  int i = blockIdx.x * blockDim.x + threadIdx.x;  // over float4 groups
  const float4 v = ((const float4*)X)[i];
  short4 o;
  o.x = f32_to_bf16(v.x); o.y = f32_to_bf16(v.y);
  o.z = f32_to_bf16(v.z); o.w = f32_to_bf16(v.w);
  ((short4*)Xb)[i] = o;
}

// ---- Kernel 2: transpose+convert W[d][e] fp32 -> WT[e][d] bf16 ----
__global__ __launch_bounds__(256) void k_transpose_w(const float* __restrict__ Wu,
                                                     const float* __restrict__ Wl,
                                                     short* __restrict__ WTu,
                                                     short* __restrict__ WTl) {
  const float* W = blockIdx.y ? Wl : Wu;
  short* WT = blockIdx.y ? WTl : WTu;
  int d = blockIdx.x, e = threadIdx.x;
  WT[e * DD + d] = f32_to_bf16(W[d * DD + e]);  // coalesced read, scattered write (tiny)
}

// ---- Kernel 3: stage 1 GEMM  Y = Xb * W  (via Y[m][n] = sum_k Xb[m][k]*WT[n][k]) ----
// Grid: (4 col-tiles of 64, 256 row-tiles of 64, 2 matrices). Block = 256 (4 waves).
// Wave w computes rows [m0+16w, m0+16w+16) x cols [n0, n0+64).
__global__ __launch_bounds__(256) void k_stage1(const short* __restrict__ Xb,
                                                const short* __restrict__ WTu,
                                                const short* __restrict__ WTl,
                                                short* __restrict__ YU,
                                                short* __restrict__ YL) {
  const short* Bt = blockIdx.z ? WTl : WTu;
  short* Y = blockIdx.z ? YL : YU;
  const int n0 = blockIdx.x * 64;
  const int m0 = blockIdx.y * 64;
  const int lane = threadIdx.x & 63;
  const int wave = threadIdx.x >> 6;
  const int r = lane & 15, quad = lane >> 4;
  const int mrow = m0 + wave * 16;

  const f32x4 z4 = {0.f, 0.f, 0.f, 0.f};
  f32x4 acc[4] = {z4, z4, z4, z4};
#pragma unroll
  for (int k0 = 0; k0 < DD; k0 += 32) {
    bf16x8 a = load_frag(Xb, mrow, k0, r, quad);
#pragma unroll
    for (int ct = 0; ct < 4; ++ct) {
      bf16x8 b = load_frag(Bt, n0 + ct * 16, k0, r, quad);
      acc[ct] = __builtin_amdgcn_mfma_f32_16x16x32_bf16(a, b, acc[ct], 0, 0, 0);
    }
  }
  // C/D layout: col = lane&15, row = quad*4 + i  (m89-verified)
#pragma unroll
  for (int ct = 0; ct < 4; ++ct)
#pragma unroll
    for (int i = 0; i < 4; ++i)
      Y[(size_t)(mrow + quad * 4 + i) * DD + n0 + ct * 16 + r] = f32_to_bf16(acc[ct][i]);
}

// ---- Kernel 4: stage 2  adj[b][p][q] = sum_e Ysel[p][e] * Xb[q][e] + bias ----
// Grid: (16 q-tiles, 16 p-tiles, 16 lists). Block = 256 (4 waves), 64x64 tile.
__global__ __launch_bounds__(256) void k_stage2(const short* __restrict__ Xb,
                                                const short* __restrict__ YU,
                                                const short* __restrict__ YL,
                                                const float* __restrict__ bu_p,
                                                const float* __restrict__ bl_p,
                                                float* __restrict__ out) {
  const int qt = blockIdx.x, pt = blockIdx.y, b = blockIdx.z;
  const int p0 = pt * 64, q0 = qt * 64;
  const int lane = threadIdx.x & 63;
  const int wave = threadIdx.x >> 6;
  const int r = lane & 15, quad = lane >> 4;
  const size_t row_off = (size_t)b * NL * DD;
  const short* Xrows = Xb + row_off;
  const short* YUr = YU + row_off;
  const short* YLr = YL + row_off;
  float* Ob = out + (size_t)b * NL * NL;
  const float bu = bu_p[0], bl = bl_p[0];
  const int prow = p0 + wave * 16;
  const f32x4 z4 = {0.f, 0.f, 0.f, 0.f};

  if (qt != pt) {
    // Pure tile: strictly above (upper) or strictly below (lower) the diagonal.
    const short* Ar = (qt > pt) ? YUr : YLr;
    const float bias = (qt > pt) ? bu : bl;
    f32x4 acc[4] = {z4, z4, z4, z4};
#pragma unroll
    for (int k0 = 0; k0 < DD; k0 += 32) {
      bf16x8 a = load_frag(Ar, prow, k0, r, quad);
#pragma unroll
      for (int ct = 0; ct < 4; ++ct) {
        bf16x8 bb = load_frag(Xrows, q0 + ct * 16, k0, r, quad);
        acc[ct] = __builtin_amdgcn_mfma_f32_16x16x32_bf16(a, bb, acc[ct], 0, 0, 0);
      }
    }
#pragma unroll
    for (int ct = 0; ct < 4; ++ct)
#pragma unroll
      for (int i = 0; i < 4; ++i)
        Ob[(size_t)(prow + quad * 4 + i) * NL + q0 + ct * 16 + r] = acc[ct][i] + bias;
  } else {
    // Diagonal tile: compute both, select per element (q>=p -> upper).
    f32x4 accU[4] = {z4, z4, z4, z4};
    f32x4 accL[4] = {z4, z4, z4, z4};
#pragma unroll
    for (int k0 = 0; k0 < DD; k0 += 32) {
      bf16x8 au = load_frag(YUr, prow, k0, r, quad);
      bf16x8 al = load_frag(YLr, prow, k0, r, quad);
#pragma unroll
      for (int ct = 0; ct < 4; ++ct) {
        bf16x8 bb = load_frag(Xrows, q0 + ct * 16, k0, r, quad);
        accU[ct] = __builtin_amdgcn_mfma_f32_16x16x32_bf16(au, bb, accU[ct], 0, 0, 0);
        accL[ct] = __builtin_amdgcn_mfma_f32_16x16x32_bf16(al, bb, accL[ct], 0, 0, 0);
      }
    }
#pragma unroll
    for (int ct = 0; ct < 4; ++ct)
#pragma unroll
      for (int i = 0; i < 4; ++i) {
        const int p = prow + quad * 4 + i;
        const int q = q0 + ct * 16 + r;
        Ob[(size_t)p * NL + q] = (q >= p) ? (accU[ct][i] + bu) : (accL[ct][i] + bl);
      }
  }
}

extern "C" void kernel_launch(void* const* d_in, const int* in_sizes, int n_in,
                              void* d_out, int out_size, void* d_ws, size_t ws_size,
                              hipStream_t stream) {
  const float* feats = (const float*)d_in[0];   // [B*N, D] fp32
  const float* Wu    = (const float*)d_in[1];   // [1, D, D]
  const float* bu    = (const float*)d_in[2];   // [1]
  const float* Wl    = (const float*)d_in[3];   // [1, D, D]
  const float* bl    = (const float*)d_in[4];   // [1]
  // d_in[5] = length (all N, unused — static shapes)
  float* out = (float*)d_out;                   // [B, N, N] fp32

  // Workspace layout (24.25 MB):
  char* ws = (char*)d_ws;
  short* Xb  = (short*)(ws);                                   // 16384*256 bf16 = 8 MB
  short* YU  = (short*)(ws + (size_t)8 * 1024 * 1024);         // 8 MB
  short* YL  = (short*)(ws + (size_t)16 * 1024 * 1024);        // 8 MB
  short* WTu = (short*)(ws + (size_t)24 * 1024 * 1024);        // 128 KB
  short* WTl = (short*)(ws + (size_t)24 * 1024 * 1024 + DD * DD * 2);

  // Prep: convert X to bf16; transpose+convert both W.
  k_convert_x<<<(BL * NL * DD / 4 + 255) / 256, 256, 0, stream>>>(feats, Xb);
  k_transpose_w<<<dim3(DD, 2), DD, 0, stream>>>(Wu, Wl, WTu, WTl);

  // Stage 1: YU = Xb*Wu, YL = Xb*Wl  (bf16 out).
  k_stage1<<<dim3(DD / 64, BL * NL / 64, 2), 256, 0, stream>>>(Xb, WTu, WTl, YU, YL);

  // Stage 2: adj tiles.
  k_stage2<<<dim3(NL / 64, NL / 64, BL), 256, 0, stream>>>(Xb, YU, YL, bu, bl, out);
}

// Round 2
// 140.998 us; speedup vs baseline: 1.4633x; 1.4633x over previous
//
#include <hip/hip_runtime.h>

// Problem constants (fixed by the reference): B=16 lists, N=1024, D=256.
#define BL 16
#define NL 1024
#define DD 256

typedef short bf16x8 __attribute__((ext_vector_type(8)));
typedef float f32x4 __attribute__((ext_vector_type(4)));

static __device__ __forceinline__ short f32_to_bf16(float f) {
  union { float f; unsigned u; } v; v.f = f;
  unsigned r = (v.u + 0x7FFFu + ((v.u >> 16) & 1u)) >> 16;  // RNE
  return (short)r;
}

// Async 16B global -> LDS (global_load_lds_dwordx4). LDS dest must be
// wave-uniform base + lane*16 (m104/m108) — our staging layout guarantees it.
static __device__ __forceinline__ void g2l16(const short* g, short* l) {
  __builtin_amdgcn_global_load_lds(
      (const __attribute__((address_space(1))) void*)g,
      (__attribute__((address_space(3))) void*)l, 16, 0, 0);
}

// Stage a 128x32 bf16 tile (rows contiguous in k) into LDS laid out row-major
// [128][32] (row stride 64 B). Thread t covers (row = t>>2 + 64*i, kchunk = t&3).
// LDS offset = i*4096B + t*16B == row*64 + kchunk*16  -> natural row-major.
static __device__ __forceinline__ void stage_tile(const short* __restrict__ gbase,
                                                  short* __restrict__ lds,
                                                  int t, int k0) {
  const int row = t >> 2, kc = t & 3;
#pragma unroll
  for (int i = 0; i < 2; ++i) {
    const short* g = gbase + (size_t)(row + 64 * i) * DD + k0 + kc * 8;
    g2l16(g, lds + i * 2048 + t * 8);
  }
}

// One BK=32 step: 8 ds_read_b128 + 16 MFMA. Wave computes 64x64 at (wm, wn).
static __device__ __forceinline__ void mma_step(const short* __restrict__ As,
                                                const short* __restrict__ Bs,
                                                int wm, int wn, int r, int quad,
                                                f32x4 acc[4][4]) {
  bf16x8 af[4], bf[4];
#pragma unroll
  for (int i = 0; i < 4; ++i) {
    af[i] = *(const bf16x8*)(As + (wm + i * 16 + r) * 32 + quad * 8);
    bf[i] = *(const bf16x8*)(Bs + (wn + i * 16 + r) * 32 + quad * 8);
  }
#pragma unroll
  for (int mt = 0; mt < 4; ++mt)
#pragma unroll
    for (int nt = 0; nt < 4; ++nt)
      acc[mt][nt] = __builtin_amdgcn_mfma_f32_16x16x32_bf16(af[mt], bf[nt], acc[mt][nt], 0, 0, 0);
}

// ---- Kernel 1: convert feats fp32 -> bf16 (row-major [B*N, D]) ----
__global__ __launch_bounds__(256) void k_convert_x(const float* __restrict__ X,
                                                   short* __restrict__ Xb) {
  int i = blockIdx.x * blockDim.x + threadIdx.x;  // over float4 groups
  const float4 v = ((const float4*)X)[i];
  short4 o;
  o.x = f32_to_bf16(v.x); o.y = f32_to_bf16(v.y);
  o.z = f32_to_bf16(v.z); o.w = f32_to_bf16(v.w);
  ((short4*)Xb)[i] = o;
}

// ---- Kernel 2: transpose+convert W[d][e] fp32 -> WT[e][d] bf16 ----
__global__ __launch_bounds__(256) void k_transpose_w(const float* __restrict__ Wu,
                                                     const float* __restrict__ Wl,
                                                     short* __restrict__ WTu,
                                                     short* __restrict__ WTl) {
  const float* W = blockIdx.y ? Wl : Wu;
  short* WT = blockIdx.y ? WTl : WTu;
  int d = blockIdx.x, e = threadIdx.x;
  WT[e * DD + d] = f32_to_bf16(W[d * DD + e]);
}

// ---- Kernel 3: stage 1 GEMM  Y = Xb * W  via Y[m][n] = sum_k Xb[m][k]*WT[n][k]
// m97 structure: 128x128 tile, LDS staging, 4 waves each 64x64.
__global__ __launch_bounds__(256) void k_stage1(const short* __restrict__ Xb,
                                                const short* __restrict__ WTu,
                                                const short* __restrict__ WTl,
                                                short* __restrict__ YU,
                                                short* __restrict__ YL) {
  __shared__ short As[128 * 32], Bs[128 * 32];
  const short* Bt = blockIdx.z ? WTl : WTu;
  short* Y = blockIdx.z ? YL : YU;
  const int m0 = blockIdx.y * 128, n0 = blockIdx.x * 128;
  const int t = threadIdx.x, lane = t & 63, wave = t >> 6;
  const int r = lane & 15, quad = lane >> 4;
  const int wm = (wave >> 1) * 64, wn = (wave & 1) * 64;
  f32x4 acc[4][4] = {};
  const short* Ag = Xb + (size_t)m0 * DD;
  const short* Bg = Bt + (size_t)n0 * DD;
  for (int k0 = 0; k0 < DD; k0 += 32) {
    stage_tile(Ag, As, t, k0);
    stage_tile(Bg, Bs, t, k0);
    __syncthreads();                 // drains vmcnt(0): LDS tiles ready
    mma_step(As, Bs, wm, wn, r, quad, acc);
    __syncthreads();                 // all waves done before next overwrite
  }
#pragma unroll
  for (int mt = 0; mt < 4; ++mt)
#pragma unroll
    for (int nt = 0; nt < 4; ++nt)
#pragma unroll
      for (int i = 0; i < 4; ++i)
        Y[(size_t)(m0 + wm + mt * 16 + quad * 4 + i) * DD + n0 + wn + nt * 16 + r] =
            f32_to_bf16(acc[mt][nt][i]);
}

// ---- Kernel 4a: stage 2 off-diagonal 128x128 tiles ----
// Exact grid (56 tiles, 16 lists): idx -> (pt, qt != pt).
__global__ __launch_bounds__(256) void k_stage2_off(const short* __restrict__ Xb,
                                                    const short* __restrict__ YU,
                                                    const short* __restrict__ YL,
                                                    const float* __restrict__ bu_p,
                                                    const float* __restrict__ bl_p,
                                                    float* __restrict__ out) {
  __shared__ short As[128 * 32], Bs[128 * 32];
  const int idx = blockIdx.x, b = blockIdx.y;
  const int pt = idx / 7, j = idx % 7;
  const int qt = j + (j >= pt ? 1 : 0);
  const size_t off = (size_t)b * NL * DD;
  const short* Ag = ((qt > pt) ? YU : YL) + off + (size_t)pt * 128 * DD;
  const short* Bg = Xb + off + (size_t)qt * 128 * DD;
  const float bias = (qt > pt) ? bu_p[0] : bl_p[0];
  const int t = threadIdx.x, lane = t & 63, wave = t >> 6;
  const int r = lane & 15, quad = lane >> 4;
  const int wm = (wave >> 1) * 64, wn = (wave & 1) * 64;
  f32x4 acc[4][4] = {};
  for (int k0 = 0; k0 < DD; k0 += 32) {
    stage_tile(Ag, As, t, k0);
    stage_tile(Bg, Bs, t, k0);
    __syncthreads();
    mma_step(As, Bs, wm, wn, r, quad, acc);
    __syncthreads();
  }
  float* Ob = out + (size_t)b * NL * NL;
  const int p0 = pt * 128 + wm, q0 = qt * 128 + wn;
#pragma unroll
  for (int mt = 0; mt < 4; ++mt)
#pragma unroll
    for (int nt = 0; nt < 4; ++nt)
#pragma unroll
      for (int i = 0; i < 4; ++i)
        Ob[(size_t)(p0 + mt * 16 + quad * 4 + i) * NL + q0 + nt * 16 + r] =
            acc[mt][nt][i] + bias;
}

// ---- Kernel 4b: stage 2 diagonal 128x128 tiles (dual accumulators) ----
__global__ __launch_bounds__(256) void k_stage2_diag(const short* __restrict__ Xb,
                                                     const short* __restrict__ YU,
                                                     const short* __restrict__ YL,
                                                     const float* __restrict__ bu_p,
                                                     const float* __restrict__ bl_p,
                                                     float* __restrict__ out) {
  __shared__ short Au[128 * 32], Al[128 * 32], Bs[128 * 32];
  const int pt = blockIdx.x, b = blockIdx.y;
  const size_t off = (size_t)b * NL * DD;
  const short* Agu = YU + off + (size_t)pt * 128 * DD;
  const short* Agl = YL + off + (size_t)pt * 128 * DD;
  const short* Bg = Xb + off + (size_t)pt * 128 * DD;
  const float bu = bu_p[0], bl = bl_p[0];
  const int t = threadIdx.x, lane = t & 63, wave = t >> 6;
  const int r = lane & 15, quad = lane >> 4;
  const int wm = (wave >> 1) * 64, wn = (wave & 1) * 64;
  f32x4 accU[4][4] = {}, accL[4][4] = {};
  for (int k0 = 0; k0 < DD; k0 += 32) {
    stage_tile(Agu, Au, t, k0);
    stage_tile(Agl, Al, t, k0);
    stage_tile(Bg, Bs, t, k0);
    __syncthreads();
    mma_step(Au, Bs, wm, wn, r, quad, accU);
    mma_step(Al, Bs, wm, wn, r, quad, accL);
    __syncthreads();
  }
  float* Ob = out + (size_t)b * NL * NL;
  const int p0 = pt * 128 + wm, q0 = pt * 128 + wn;
#pragma unroll
  for (int mt = 0; mt < 4; ++mt)
#pragma unroll
    for (int nt = 0; nt < 4; ++nt)
#pragma unroll
      for (int i = 0; i < 4; ++i) {
        const int p = p0 + mt * 16 + quad * 4 + i;
        const int q = q0 + nt * 16 + r;
        Ob[(size_t)p * NL + q] =
            (q >= p) ? (accU[mt][nt][i] + bu) : (accL[mt][nt][i] + bl);
      }
}

extern "C" void kernel_launch(void* const* d_in, const int* in_sizes, int n_in,
                              void* d_out, int out_size, void* d_ws, size_t ws_size,
                              hipStream_t stream) {
  const float* feats = (const float*)d_in[0];   // [B*N, D] fp32
  const float* Wu    = (const float*)d_in[1];   // [1, D, D]
  const float* bu    = (const float*)d_in[2];   // [1]
  const float* Wl    = (const float*)d_in[3];   // [1, D, D]
  const float* bl    = (const float*)d_in[4];   // [1]
  float* out = (float*)d_out;                   // [B, N, N] fp32

  char* ws = (char*)d_ws;
  short* Xb  = (short*)(ws);                                   // 8 MB
  short* YU  = (short*)(ws + (size_t)8 * 1024 * 1024);         // 8 MB
  short* YL  = (short*)(ws + (size_t)16 * 1024 * 1024);        // 8 MB
  short* WTu = (short*)(ws + (size_t)24 * 1024 * 1024);        // 128 KB
  short* WTl = (short*)(ws + (size_t)24 * 1024 * 1024 + DD * DD * 2);

  k_convert_x<<<(BL * NL * DD / 4 + 255) / 256, 256, 0, stream>>>(feats, Xb);
  k_transpose_w<<<dim3(DD, 2), DD, 0, stream>>>(Wu, Wl, WTu, WTl);

  // Stage 1: YU = Xb*Wu, YL = Xb*Wl  (bf16 out). 128x128 tiles.
  k_stage1<<<dim3(DD / 128, BL * NL / 128, 2), 256, 0, stream>>>(Xb, WTu, WTl, YU, YL);

  // Stage 2: off-diagonal then diagonal tiles.
  k_stage2_off<<<dim3(56, BL), 256, 0, stream>>>(Xb, YU, YL, bu, bl, out);
  k_stage2_diag<<<dim3(8, BL), 256, 0, stream>>>(Xb, YU, YL, bu, bl, out);
}

// Round 3
// 134.373 us; speedup vs baseline: 1.5354x; 1.0493x over previous
//
#include <hip/hip_runtime.h>

// Problem constants (fixed by the reference): B=16 lists, N=1024, D=256.
#define BL 16
#define NL 1024
#define DD 256

typedef short bf16x8 __attribute__((ext_vector_type(8)));
typedef float f32x4 __attribute__((ext_vector_type(4)));

static __device__ __forceinline__ short f32_to_bf16(float f) {
  union { float f; unsigned u; } v; v.f = f;
  unsigned r = (v.u + 0x7FFFu + ((v.u >> 16) & 1u)) >> 16;  // RNE
  return (short)r;
}

// Async 16B global -> LDS. LDS dest must be wave-uniform base + lane*16
// (m104/m108); staging layout below guarantees lane offset = lane*16.
static __device__ __forceinline__ void g2l16(const short* g, short* l) {
  __builtin_amdgcn_global_load_lds(
      (const __attribute__((address_space(1))) void*)g,
      (__attribute__((address_space(3))) void*)l, 16, 0, 0);
}

// Stage a 128x32 bf16 sub-chunk into LDS [128][32] row-major (row stride 64B).
// Thread t covers (row = t>>2 + 64*i, kchunk = t&3); LDS off = i*4096B + t*16B.
static __device__ __forceinline__ void stage_tile(const short* __restrict__ gbase,
                                                  short* __restrict__ lds,
                                                  int t, int k0) {
  const int row = t >> 2, kc = t & 3;
#pragma unroll
  for (int i = 0; i < 2; ++i) {
    const short* g = gbase + (size_t)(row + 64 * i) * DD + k0 + kc * 8;
    g2l16(g, lds + i * 2048 + t * 8);
  }
}

// One 32-wide k step: 8 ds_read_b128 + 16 MFMA. Wave computes 64x64 at (wm,wn).
static __device__ __forceinline__ void mma_step(const short* __restrict__ As,
                                                const short* __restrict__ Bs,
                                                int wm, int wn, int r, int quad,
                                                f32x4 acc[4][4]) {
  bf16x8 af[4], bf[4];
#pragma unroll
  for (int i = 0; i < 4; ++i) {
    af[i] = *(const bf16x8*)(As + (wm + i * 16 + r) * 32 + quad * 8);
    bf[i] = *(const bf16x8*)(Bs + (wn + i * 16 + r) * 32 + quad * 8);
  }
#pragma unroll
  for (int mt = 0; mt < 4; ++mt)
#pragma unroll
    for (int nt = 0; nt < 4; ++nt)
      acc[mt][nt] = __builtin_amdgcn_mfma_f32_16x16x32_bf16(af[mt], bf[nt], acc[mt][nt], 0, 0, 0);
}

// ---- Kernel 1: prep. Blocks [0,4096): X fp32->bf16. [4096,4608): W transpose.
__global__ __launch_bounds__(256) void k_prep(const float* __restrict__ X,
                                              const float* __restrict__ Wu,
                                              const float* __restrict__ Wl,
                                              short* __restrict__ Xb,
                                              short* __restrict__ WTu,
                                              short* __restrict__ WTl) {
  const int bid = blockIdx.x;
  if (bid < 4096) {
    int i = bid * 256 + threadIdx.x;  // float4 groups over 16384*256 floats
    const float4 v = ((const float4*)X)[i];
    short4 o;
    o.x = f32_to_bf16(v.x); o.y = f32_to_bf16(v.y);
    o.z = f32_to_bf16(v.z); o.w = f32_to_bf16(v.w);
    ((short4*)Xb)[i] = o;
  } else {
    const int id = bid - 4096;           // [0,512)
    const int z = id >> 8, d = id & 255; // matrix, source row
    const float* W = z ? Wl : Wu;
    short* WT = z ? WTl : WTu;
    const int e = threadIdx.x;
    WT[e * DD + d] = f32_to_bf16(W[d * DD + e]);
  }
}

// ---- Kernel 2: stage 1 GEMM  Y = Xb * W  via Y[m][n] = sum_k Xb[m][k]*WT[n][k]
// 128x128 tile, BK=64 (two 32-sub-chunks per barrier pair), 4 waves of 64x64.
__global__ __launch_bounds__(256) void k_stage1(const short* __restrict__ Xb,
                                                const short* __restrict__ WTu,
                                                const short* __restrict__ WTl,
                                                short* __restrict__ YU,
                                                short* __restrict__ YL) {
  __shared__ short As[2][128 * 32], Bs[2][128 * 32];
  const short* Bt = blockIdx.z ? WTl : WTu;
  short* Y = blockIdx.z ? YL : YU;
  const int m0 = blockIdx.y * 128, n0 = blockIdx.x * 128;
  const int t = threadIdx.x, lane = t & 63, wave = t >> 6;
  const int r = lane & 15, quad = lane >> 4;
  const int wm = (wave >> 1) * 64, wn = (wave & 1) * 64;
  f32x4 acc[4][4] = {};
  const short* Ag = Xb + (size_t)m0 * DD;
  const short* Bg = Bt + (size_t)n0 * DD;
  for (int k0 = 0; k0 < DD; k0 += 64) {
    stage_tile(Ag, As[0], t, k0);
    stage_tile(Ag, As[1], t, k0 + 32);
    stage_tile(Bg, Bs[0], t, k0);
    stage_tile(Bg, Bs[1], t, k0 + 32);
    __syncthreads();
    mma_step(As[0], Bs[0], wm, wn, r, quad, acc);
    mma_step(As[1], Bs[1], wm, wn, r, quad, acc);
    __syncthreads();
  }
#pragma unroll
  for (int mt = 0; mt < 4; ++mt)
#pragma unroll
    for (int nt = 0; nt < 4; ++nt)
#pragma unroll
      for (int i = 0; i < 4; ++i)
        Y[(size_t)(m0 + wm + mt * 16 + quad * 4 + i) * DD + n0 + wn + nt * 16 + r] =
            f32_to_bf16(acc[mt][nt][i]);
}

// ---- Kernel 3: stage 2 off-diagonal 128x128 tiles (56 tiles x 16 lists) ----
__global__ __launch_bounds__(256) void k_stage2_off(const short* __restrict__ Xb,
                                                    const short* __restrict__ YU,
                                                    const short* __restrict__ YL,
                                                    const float* __restrict__ bu_p,
                                                    const float* __restrict__ bl_p,
                                                    float* __restrict__ out) {
  __shared__ short As[2][128 * 32], Bs[2][128 * 32];
  const int idx = blockIdx.x, b = blockIdx.y;
  const int pt = idx / 7, j = idx % 7;
  const int qt = j + (j >= pt ? 1 : 0);
  const size_t off = (size_t)b * NL * DD;
  const short* Ag = ((qt > pt) ? YU : YL) + off + (size_t)pt * 128 * DD;
  const short* Bg = Xb + off + (size_t)qt * 128 * DD;
  const float bias = (qt > pt) ? bu_p[0] : bl_p[0];
  const int t = threadIdx.x, lane = t & 63, wave = t >> 6;
  const int r = lane & 15, quad = lane >> 4;
  const int wm = (wave >> 1) * 64, wn = (wave & 1) * 64;
  const f32x4 binit = {bias, bias, bias, bias};
  f32x4 acc[4][4];
#pragma unroll
  for (int mt = 0; mt < 4; ++mt)
#pragma unroll
    for (int nt = 0; nt < 4; ++nt) acc[mt][nt] = binit;
  for (int k0 = 0; k0 < DD; k0 += 64) {
    stage_tile(Ag, As[0], t, k0);
    stage_tile(Ag, As[1], t, k0 + 32);
    stage_tile(Bg, Bs[0], t, k0);
    stage_tile(Bg, Bs[1], t, k0 + 32);
    __syncthreads();
    mma_step(As[0], Bs[0], wm, wn, r, quad, acc);
    mma_step(As[1], Bs[1], wm, wn, r, quad, acc);
    __syncthreads();
  }
  float* Ob = out + (size_t)b * NL * NL;
  const int p0 = pt * 128 + wm, q0 = qt * 128 + wn;
#pragma unroll
  for (int mt = 0; mt < 4; ++mt)
#pragma unroll
    for (int nt = 0; nt < 4; ++nt)
#pragma unroll
      for (int i = 0; i < 4; ++i)
        Ob[(size_t)(p0 + mt * 16 + quad * 4 + i) * NL + q0 + nt * 16 + r] =
            acc[mt][nt][i];
}

// ---- Kernel 4: stage 2 diagonal tiles (dual accumulators) ----
__global__ __launch_bounds__(256) void k_stage2_diag(const short* __restrict__ Xb,
                                                     const short* __restrict__ YU,
                                                     const short* __restrict__ YL,
                                                     const float* __restrict__ bu_p,
                                                     const float* __restrict__ bl_p,
                                                     float* __restrict__ out) {
  __shared__ short Au[2][128 * 32], Al[2][128 * 32], Bs[2][128 * 32];
  const int pt = blockIdx.x, b = blockIdx.y;
  const size_t off = (size_t)b * NL * DD;
  const short* Agu = YU + off + (size_t)pt * 128 * DD;
  const short* Agl = YL + off + (size_t)pt * 128 * DD;
  const short* Bg = Xb + off + (size_t)pt * 128 * DD;
  const float bu = bu_p[0], bl = bl_p[0];
  const int t = threadIdx.x, lane = t & 63, wave = t >> 6;
  const int r = lane & 15, quad = lane >> 4;
  const int wm = (wave >> 1) * 64, wn = (wave & 1) * 64;
  f32x4 accU[4][4] = {}, accL[4][4] = {};
  for (int k0 = 0; k0 < DD; k0 += 64) {
    stage_tile(Agu, Au[0], t, k0);
    stage_tile(Agu, Au[1], t, k0 + 32);
    stage_tile(Agl, Al[0], t, k0);
    stage_tile(Agl, Al[1], t, k0 + 32);
    stage_tile(Bg, Bs[0], t, k0);
    stage_tile(Bg, Bs[1], t, k0 + 32);
    __syncthreads();
    mma_step(Au[0], Bs[0], wm, wn, r, quad, accU);
    mma_step(Al[0], Bs[0], wm, wn, r, quad, accL);
    mma_step(Au[1], Bs[1], wm, wn, r, quad, accU);
    mma_step(Al[1], Bs[1], wm, wn, r, quad, accL);
    __syncthreads();
  }
  float* Ob = out + (size_t)b * NL * NL;
  const int p0 = pt * 128 + wm, q0 = pt * 128 + wn;
#pragma unroll
  for (int mt = 0; mt < 4; ++mt)
#pragma unroll
    for (int nt = 0; nt < 4; ++nt)
#pragma unroll
      for (int i = 0; i < 4; ++i) {
        const int p = p0 + mt * 16 + quad * 4 + i;
        const int q = q0 + nt * 16 + r;
        Ob[(size_t)p * NL + q] =
            (q >= p) ? (accU[mt][nt][i] + bu) : (accL[mt][nt][i] + bl);
      }
}

extern "C" void kernel_launch(void* const* d_in, const int* in_sizes, int n_in,
                              void* d_out, int out_size, void* d_ws, size_t ws_size,
                              hipStream_t stream) {
  const float* feats = (const float*)d_in[0];   // [B*N, D] fp32
  const float* Wu    = (const float*)d_in[1];   // [1, D, D]
  const float* bu    = (const float*)d_in[2];   // [1]
  const float* Wl    = (const float*)d_in[3];   // [1, D, D]
  const float* bl    = (const float*)d_in[4];   // [1]
  float* out = (float*)d_out;                   // [B, N, N] fp32

  char* ws = (char*)d_ws;
  short* Xb  = (short*)(ws);                                   // 8 MB
  short* YU  = (short*)(ws + (size_t)8 * 1024 * 1024);         // 8 MB
  short* YL  = (short*)(ws + (size_t)16 * 1024 * 1024);        // 8 MB
  short* WTu = (short*)(ws + (size_t)24 * 1024 * 1024);        // 128 KB
  short* WTl = (short*)(ws + (size_t)24 * 1024 * 1024 + DD * DD * 2);

  // Prep: X->bf16 (4096 blocks) + W transpose (512 blocks), one dispatch.
  k_prep<<<4096 + 512, 256, 0, stream>>>(feats, Wu, Wl, Xb, WTu, WTl);

  // Stage 1: YU = Xb*Wu, YL = Xb*Wl  (bf16 out).
  k_stage1<<<dim3(DD / 128, BL * NL / 128, 2), 256, 0, stream>>>(Xb, WTu, WTl, YU, YL);

  // Stage 2: off-diagonal then diagonal tiles.
  k_stage2_off<<<dim3(56, BL), 256, 0, stream>>>(Xb, YU, YL, bu, bl, out);
  k_stage2_diag<<<dim3(8, BL), 256, 0, stream>>>(Xb, YU, YL, bu, bl, out);
}